// Round 21
// baseline (450.005 us; speedup 1.0000x reference)
//
#include <hip/hip_runtime.h>
#include <stdint.h>

// Round 21: attn_gemm2 rebuilt for OCCUPANCY. R20 analysis: unified VGPR+AGPR
// ~120/wave -> 16 waves/CU by regs -> only ONE 12-wave block resident (occ 34%,
// latency-bound). Fix: 384-thread (6-wave) blocks, 2 heads/wave serial, QK/
// softmax/PV split into two independent it-column halves (c[4][2] not [4][4])
// -> peak unified regs ~85 <= 102 cap (launch_bounds(384,5)) -> 3 blocks/CU
// (18 waves, +50%). LDS 3x49KB=147<=160KB. gemm1/prep frozen (R12/R13).

typedef __attribute__((ext_vector_type(4))) float f32x4;
typedef __attribute__((ext_vector_type(4))) short s16x4;
typedef __attribute__((ext_vector_type(8))) short s16x8;

#define DEVI static __device__ __forceinline__

DEVI unsigned short f2bf(float f) {
  union { float f; uint32_t u; } v; v.f = f;
  return (unsigned short)((v.u + 0x7FFFu + ((v.u >> 16) & 1u)) >> 16);
}

DEVI uint32_t pk2(float lo, float hi) {
  return (uint32_t)f2bf(lo) | ((uint32_t)f2bf(hi) << 16);
}

DEVI f32x4 zero4() { f32x4 z; z[0] = 0.f; z[1] = 0.f; z[2] = 0.f; z[3] = 0.f; return z; }

#if defined(__has_builtin)
#if __has_builtin(__builtin_amdgcn_mfma_f32_16x16x16bf16_1k)
#define MFMA16_BUILTIN 1
#endif
#if __has_builtin(__builtin_amdgcn_global_load_lds)
#define HAS_GLLDS 1
#endif
#endif

DEVI f32x4 mfma16(s16x4 a, s16x4 b, f32x4 c) {
#ifdef MFMA16_BUILTIN
  return __builtin_amdgcn_mfma_f32_16x16x16bf16_1k(a, b, c, 0, 0, 0);
#else
  asm volatile("v_mfma_f32_16x16x16_bf16 %0, %1, %2, %0" : "+v"(c) : "v"(a), "v"(b));
  return c;
#endif
}

DEVI f32x4 mfma32(s16x8 a, s16x8 b, f32x4 c) {
  return __builtin_amdgcn_mfma_f32_16x16x32_bf16(a, b, c, 0, 0, 0);
}

DEVI void stage1k(const unsigned short* g_lane, unsigned short* lds_base) {
#ifdef HAS_GLLDS
  __builtin_amdgcn_global_load_lds(
      (const __attribute__((address_space(1))) unsigned int*)g_lane,
      (__attribute__((address_space(3))) unsigned int*)lds_base, 16, 0, 0);
#else
  *(s16x8*)(lds_base + (threadIdx.x & 63) * 8) = *(const s16x8*)g_lane;
#endif
}

__global__ void fill_val(float* o, int n, float v) {
  int t = blockIdx.x * 256 + threadIdx.x;
  if (t < n) o[t] = v;
}

// ---------------- merged prep (R13 verbatim) ----------------
__global__ __launch_bounds__(256) void prep_all(
    const float* __restrict__ x, unsigned short* __restrict__ xb,
    const float* __restrict__ Wqkv, unsigned short* __restrict__ WqkvT,
    const float* __restrict__ Wm, unsigned short* __restrict__ WmT,
    const float* __restrict__ bqkv, float* __restrict__ bqkvs,
    const float* __restrict__ rel, float* __restrict__ biasF) {
  const int b = blockIdx.x;
  if (b < 2048) {
    const size_t nchunk = 131072UL * 384 / 8;
    for (size_t i = (size_t)b * 256 + threadIdx.x; i < nchunk; i += 2048UL * 256) {
      f32x4 a = *(const f32x4*)(x + i * 8);
      f32x4 c = *(const f32x4*)(x + i * 8 + 4);
      s16x8 p;
      p[0] = (short)f2bf(a[0]); p[1] = (short)f2bf(a[1]);
      p[2] = (short)f2bf(a[2]); p[3] = (short)f2bf(a[3]);
      p[4] = (short)f2bf(c[0]); p[5] = (short)f2bf(c[1]);
      p[6] = (short)f2bf(c[2]); p[7] = (short)f2bf(c[3]);
      *(s16x8*)(xb + i * 8) = p;
    }
  } else if (b == 2048) {
    for (int t = threadIdx.x; t < 1152; t += 256)
      bqkvs[t] = bqkv[t] * ((t < 384) ? 0.17677669529663687f : 1.0f);
  } else if (b < 2097) {
    int t = (b - 2049) * 256 + threadIdx.x;  // 12288
    if (t < 12288) {
      int h = t >> 10;
      int r = (t >> 6) & 15;
      int lane = t & 63;
      int jt = r >> 2, it = r & 3;
      int lg = lane >> 4, lr = lane & 15;
      int i = it * 16 + lr;
#pragma unroll
      for (int e = 0; e < 4; ++e) {
        int j = jt * 16 + lg * 4 + e;
        int idx = ((i >> 3) - (j >> 3) + 7) * 15 + ((i & 7) - (j & 7) + 7);
        biasF[t * 4 + e] = rel[idx * 12 + h];
      }
    }
  } else if (b < 2673) {
    int t = (b - 2097) * 256 + threadIdx.x;  // 147456
    int n = t / 384, k = t - n * 384;
    WmT[t] = f2bf(Wm[(size_t)k * 384 + n]);
  } else {
    int t = (b - 2673) * 256 + threadIdx.x;  // 442368
    int n = t / 384, k = t - n * 384;
    float s = (n < 384) ? 0.17677669529663687f : 1.0f;
    WqkvT[t] = f2bf(Wqkv[(size_t)k * 1152 + n] * s);
  }
}

// ---------------- GEMM1 (R12 verbatim, counted-vmcnt dbuf + T2 swizzle) ----------
template <bool QKV_EPI>
__global__ __launch_bounds__(512, 4) void gemm_k(const unsigned short* __restrict__ A,
                                                 const unsigned short* __restrict__ BT,
                                                 const float* __restrict__ bias,
                                                 void* __restrict__ Cv) {
  constexpr int K = 384;
  constexpr int NT = QKV_EPI ? 9 : 3;
  constexpr int N = NT * 128;
  __shared__ unsigned short sm[2][16384];
  const int bid = blockIdx.x;
  const int swz = (bid & 7) * (NT * 128) + (bid >> 3);
  const int n0 = (swz % NT) * 128;
  const int m0 = (swz / NT) * 128;
  const int tid = threadIdx.x;
  const int lane = tid & 63, wv = tid >> 6;
  const int wr = wv >> 2, wc = wv & 3;
  const int lg = lane >> 4, lr = lane & 15;

  const int scol = ((lane & 7) ^ (lane >> 3)) * 8;
  const unsigned short* Ag = A + (size_t)(m0 + wv * 16 + (lane >> 3)) * K + scol;
  const unsigned short* Bg = BT + (size_t)(n0 + wv * 16 + (lane >> 3)) * K + scol;

  f32x4 acc[4][2];
#pragma unroll
  for (int i = 0; i < 4; ++i)
#pragma unroll
    for (int j = 0; j < 2; ++j) acc[i][j] = zero4();

  auto STAGE = [&](int buf, int k0) {
#pragma unroll
    for (int c2 = 0; c2 < 2; ++c2)
      stage1k(Ag + (size_t)(c2 * 8) * K + k0, &sm[buf][(wv * 16 + c2 * 8) * 64]);
#pragma unroll
    for (int c2 = 0; c2 < 2; ++c2)
      stage1k(Bg + (size_t)(c2 * 8) * K + k0, &sm[buf][8192 + (wv * 16 + c2 * 8) * 64]);
  };
  const int sa = (lr & 7) << 3;
  auto COMPUTE = [&](int buf) {
#pragma unroll
    for (int kk = 0; kk < 64; kk += 32) {
      s16x8 af[4], bf[2];
#pragma unroll
      for (int mt = 0; mt < 4; ++mt)
        af[mt] = *(const s16x8*)&sm[buf][(wr * 64 + 16 * mt + lr) * 64 + ((kk + 8 * lg) ^ sa)];
#pragma unroll
      for (int nt = 0; nt < 2; ++nt)
        bf[nt] = *(const s16x8*)&sm[buf][8192 + (wc * 32 + 16 * nt + lr) * 64 + ((kk + 8 * lg) ^ sa)];
#pragma unroll
      for (int mt = 0; mt < 4; ++mt)
#pragma unroll
        for (int nt = 0; nt < 2; ++nt)
          acc[mt][nt] = mfma32(af[mt], bf[nt], acc[mt][nt]);
    }
  };

  STAGE(0, 0);
  int cur = 0;
#pragma unroll 1
  for (int t = 0; t < 5; ++t) {
    STAGE(cur ^ 1, (t + 1) * 64);
    asm volatile("s_waitcnt vmcnt(4)" ::: "memory");
    __builtin_amdgcn_sched_barrier(0);
    __builtin_amdgcn_s_barrier();
    __builtin_amdgcn_sched_barrier(0);
    COMPUTE(cur);
    __builtin_amdgcn_sched_barrier(0);
    __builtin_amdgcn_s_barrier();
    cur ^= 1;
  }
  asm volatile("s_waitcnt vmcnt(0)" ::: "memory");
  __builtin_amdgcn_sched_barrier(0);
  __builtin_amdgcn_s_barrier();
  __builtin_amdgcn_sched_barrier(0);
  COMPUTE(cur);

  const int crow = m0 + wr * 64 + 4 * lg;
  const int ccol = n0 + wc * 32 + lr;
  if constexpr (QKV_EPI) {
    const int sel = n0 / 384;
    unsigned short* qkv = (unsigned short*)Cv;
    if (sel < 2) {
      unsigned short* tile = &sm[0][0];
#pragma unroll
      for (int nt = 0; nt < 2; ++nt) {
        const int cc = wc * 32 + 16 * nt + lr;
        const float bv = bias[n0 + cc];
#pragma unroll
        for (int mt = 0; mt < 4; ++mt) {
#pragma unroll
          for (int e = 0; e < 4; ++e) {
            const int r = wr * 64 + 16 * mt + 4 * lg + e;
            tile[r * 128 + (cc ^ ((r & 7) << 3))] = f2bf(acc[mt][nt][e] + bv);
          }
        }
      }
      __syncthreads();
      const int hbase = (n0 - sel * 384) >> 5;
      const int tr = wv * 16 + (lane >> 2);
      const int gtok = m0 + tr;
      const int w2 = gtok >> 6, t0r = gtok & 63;
#pragma unroll
      for (int hh = 0; hh < 4; ++hh) {
        const int chunk = hh * 4 + (lane & 3);
        s16x8 v = *(const s16x8*)&tile[tr * 128 + ((chunk * 8) ^ ((tr & 7) << 3))];
        unsigned short* dst = qkv + (((size_t)w2 * 12 + hbase + hh) * 3 + sel) * 2048 +
                              t0r * 32 + (lane & 3) * 8;
        *(s16x8*)dst = v;
      }
    } else {
      const int window = crow >> 6;
      const int t0 = crow & 63;
#pragma unroll
      for (int nt = 0; nt < 2; ++nt) {
        const int col = ccol + 16 * nt;
        const int hcol = col - 768;
        const int h = hcol >> 5, d = hcol & 31;
        const float bv = bias[col];
        unsigned short* base = qkv + (((size_t)window * 12 + h) * 3 + 2) * 2048;
#pragma unroll
        for (int mt = 0; mt < 4; ++mt) {
          s16x4 pk;
#pragma unroll
          for (int e = 0; e < 4; ++e) pk[e] = (short)f2bf(acc[mt][nt][e] + bv);
          *(s16x4*)&base[d * 64 + t0 + 16 * mt] = pk;
        }
      }
    }
  } else {
    float* C = (float*)Cv;
#pragma unroll
    for (int mt = 0; mt < 4; ++mt)
#pragma unroll
      for (int nt = 0; nt < 2; ++nt) {
        const int col = ccol + 16 * nt;
        const float bv = bias[col];
#pragma unroll
        for (int e = 0; e < 4; ++e)
          C[(size_t)(crow + 16 * mt + e) * N + col] = acc[mt][nt][e] + bv;
      }
  }
}

// ---------------- fused attention + GEMM2: 6 waves (384 thr) per window ----------
// Phase 1: wave wv handles heads 2wv, 2wv+1 serially; each head split into two
// it-column halves (c[4][2] accumulator) -> peak unified regs ~85.
// Phase 2: wave wv -> out cols [wv*64, +64) in two acc[4][2] sub-passes.
__global__ __launch_bounds__(384, 5) void attn_gemm2_k(const unsigned short* __restrict__ qkv,
                                                       const float* __restrict__ biasF,
                                                       const unsigned short* __restrict__ WmT,
                                                       const float* __restrict__ bm,
                                                       float* __restrict__ out) {
  __shared__ unsigned short att_s[64 * 392];  // 50176 B
  const int lane = threadIdx.x & 63;
  const int wv = threadIdx.x >> 6;  // 0..5
  const int window = blockIdx.x;    // [0, 2048)
  const int lg = lane >> 4, lr = lane & 15;

#pragma unroll 1
  for (int hp = 0; hp < 2; ++hp) {
    const int h = wv * 2 + hp;
    const unsigned short* hb = qkv + ((size_t)window * 12 + h) * 6144;
    const unsigned short* Qh = hb;
    const unsigned short* Kh = hb + 2048;
    const unsigned short* Vth = hb + 4096;

    s16x8 ka[4];
#pragma unroll
    for (int jt = 0; jt < 4; ++jt)
      ka[jt] = *(const s16x8*)&Kh[(jt * 16 + lr) * 32 + 8 * lg];

#pragma unroll 1
    for (int itp = 0; itp < 2; ++itp) {
      // QK^T for columns it = itp*2 + {0,1}
      s16x8 qb[2];
#pragma unroll
      for (int i2 = 0; i2 < 2; ++i2)
        qb[i2] = *(const s16x8*)&Qh[((itp * 2 + i2) * 16 + lr) * 32 + 8 * lg];

      f32x4 c[4][2];
#pragma unroll
      for (int a = 0; a < 4; ++a)
#pragma unroll
        for (int b2 = 0; b2 < 2; ++b2) c[a][b2] = zero4();

#pragma unroll
      for (int jt = 0; jt < 4; ++jt)
#pragma unroll
        for (int i2 = 0; i2 < 2; ++i2)
          c[jt][i2] = mfma32(ka[jt], qb[i2], c[jt][i2]);

      const f32x4* bF = (const f32x4*)biasF + ((size_t)h * 16) * 64 + lane;
#pragma unroll
      for (int jt = 0; jt < 4; ++jt)
#pragma unroll
        for (int i2 = 0; i2 < 2; ++i2)
          c[jt][i2] += bF[(jt * 4 + itp * 2 + i2) * 64];

      // softmax over j per column (columns independent)
      s16x4 pb[4][2];
#pragma unroll
      for (int i2 = 0; i2 < 2; ++i2) {
        float m = -3.0e38f;
#pragma unroll
        for (int jt = 0; jt < 4; ++jt)
#pragma unroll
          for (int e = 0; e < 4; ++e) m = fmaxf(m, c[jt][i2][e]);
        m = fmaxf(m, __shfl_xor(m, 16));
        m = fmaxf(m, __shfl_xor(m, 32));
        float s = 0.f;
#pragma unroll
        for (int jt = 0; jt < 4; ++jt)
#pragma unroll
          for (int e = 0; e < 4; ++e) {
            float p = __expf(c[jt][i2][e] - m);
            c[jt][i2][e] = p;
            s += p;
          }
        s += __shfl_xor(s, 16);
        s += __shfl_xor(s, 32);
        const float inv = 1.f / s;
#pragma unroll
        for (int jt = 0; jt < 4; ++jt) {
          s16x4 pk;
#pragma unroll
          for (int e = 0; e < 4; ++e) pk[e] = (short)f2bf(c[jt][i2][e] * inv);
          pb[jt][i2] = pk;
        }
      }

      // PV for these 2 columns (va loaded per-jt, R15 style: only 4 live regs)
      f32x4 o[2][2];
#pragma unroll
      for (int a = 0; a < 2; ++a)
#pragma unroll
        for (int b2 = 0; b2 < 2; ++b2) o[a][b2] = zero4();

#pragma unroll
      for (int jt = 0; jt < 4; ++jt) {
        s16x4 va[2];
#pragma unroll
        for (int dt = 0; dt < 2; ++dt)
          va[dt] = *(const s16x4*)&Vth[(dt * 16 + lr) * 64 + jt * 16 + 4 * lg];
#pragma unroll
        for (int dt = 0; dt < 2; ++dt)
#pragma unroll
          for (int i2 = 0; i2 < 2; ++i2)
            o[dt][i2] = mfma16(va[dt], pb[jt][i2], o[dt][i2]);
      }

      // R14 4-lane transpose -> att_s, per column group (it = itp*2+i2)
#pragma unroll
      for (int i2 = 0; i2 < 2; ++i2) {
        const int it = itp * 2 + i2;
        const uint32_t p0 = pk2(o[0][i2][0], o[0][i2][1]);
        const uint32_t p1 = pk2(o[0][i2][2], o[0][i2][3]);
        const uint32_t q0 = pk2(o[1][i2][0], o[1][i2][1]);
        const uint32_t q1 = pk2(o[1][i2][2], o[1][i2][3]);

        const uint32_t x16_0 = __shfl_xor((int)(lg == 2 ? q0 : p0), 16);
        const uint32_t x16_1 = __shfl_xor((int)(lg == 2 ? q1 : p1), 16);
        const uint32_t x32_0 = __shfl_xor((int)(lg == 0 ? q0 : p0), 32);
        const uint32_t x32_1 = __shfl_xor((int)(lg == 0 ? q1 : p1), 32);
        const uint32_t x48_0 = __shfl_xor((int)(lg == 1 ? q0 : p0), 48);
        const uint32_t x48_1 = __shfl_xor((int)(lg == 1 ? q1 : p1), 48);

        uint32_t w[4];
        w[0] = lg == 0 ? p0 : lg == 1 ? x48_0 : lg == 2 ? x32_0 : x16_0;
        w[1] = lg == 0 ? p1 : lg == 1 ? x48_1 : lg == 2 ? x32_1 : x16_1;
        w[2] = lg == 0 ? x16_0 : lg == 1 ? x32_0 : lg == 2 ? x48_0 : q0;
        w[3] = lg == 0 ? x16_1 : lg == 1 ? x32_1 : lg == 2 ? x48_1 : q1;

        *(uint4*)&att_s[(size_t)(it * 16 + lr) * 392 + h * 32 + 8 * lg] =
            make_uint4(w[0], w[1], w[2], w[3]);
      }
    }
  }

  __syncthreads();

  // ---- phase 2: GEMM2. wave wv -> cols [wv*64, +64) in two sub-passes of 32.
  float* ob = out + (size_t)window * 64 * 384;
#pragma unroll 1
  for (int np = 0; np < 2; ++np) {
    const int n0w = wv * 64 + np * 32;
    f32x4 acc[4][2];
#pragma unroll
    for (int mt = 0; mt < 4; ++mt)
#pragma unroll
      for (int nt = 0; nt < 2; ++nt) acc[mt][nt] = zero4();

#pragma unroll 2
    for (int ks = 0; ks < 12; ++ks) {
      s16x8 af[4], bf[2];
#pragma unroll
      for (int mt = 0; mt < 4; ++mt)
        af[mt] = *(const s16x8*)&att_s[(16 * mt + lr) * 392 + ks * 32 + 8 * lg];
#pragma unroll
      for (int nt = 0; nt < 2; ++nt)
        bf[nt] = *(const s16x8*)&WmT[(size_t)(n0w + 16 * nt + lr) * 384 + ks * 32 + 8 * lg];
#pragma unroll
      for (int mt = 0; mt < 4; ++mt)
#pragma unroll
        for (int nt = 0; nt < 2; ++nt)
          acc[mt][nt] = mfma32(af[mt], bf[nt], acc[mt][nt]);
    }

#pragma unroll
    for (int mt = 0; mt < 4; ++mt)
#pragma unroll
      for (int nt = 0; nt < 2; ++nt) {
        const int col = n0w + 16 * nt + lr;
        const float bv = bm[col];
#pragma unroll
        for (int e = 0; e < 4; ++e)
          ob[(size_t)(16 * mt + 4 * lg + e) * 384 + col] = acc[mt][nt][e] + bv;
      }
  }
}

extern "C" void kernel_launch(void* const* d_in, const int* in_sizes, int n_in,
                              void* d_out, int out_size, void* d_ws, size_t ws_size,
                              hipStream_t stream) {
  const float* x = (const float*)d_in[0];
  const float* Wqkv = (const float*)d_in[1];
  const float* bqkv = (const float*)d_in[2];
  const float* Wm = (const float*)d_in[3];
  const float* bm = (const float*)d_in[4];
  const float* rel = (const float*)d_in[5];

  const size_t M = 131072;  // B*G*P
  char* ws = (char*)d_ws;
  size_t off = 0;
  unsigned short* qkv = (unsigned short*)(ws + off);   off += M * 1152 * 2;  // 302 MB
  unsigned short* xb = (unsigned short*)(ws + off);    off += M * 384 * 2;   // 100 MB
  unsigned short* WqkvT = (unsigned short*)(ws + off); off += 1152 * 384 * 2;
  unsigned short* WmT = (unsigned short*)(ws + off);   off += 384 * 384 * 2;
  float* biasF = (float*)(ws + off);                   off += 12 * 16 * 64 * 4 * 4;
  float* bqkvs = (float*)(ws + off);                   off += 1152 * 4;

  if (ws_size < off) {
    fill_val<<<(out_size + 255) / 256, 256, 0, stream>>>((float*)d_out, out_size, 12345.0f);
    return;
  }

  prep_all<<<4401, 256, 0, stream>>>(x, xb, Wqkv, WqkvT, Wm, WmT, bqkv, bqkvs, rel, biasF);
  gemm_k<true><<<9216, 512, 0, stream>>>(xb, WqkvT, bqkvs, qkv);
  attn_gemm2_k<<<2048, 384, 0, stream>>>(qkv, biasF, WmT, bm, (float*)d_out);
}

// Round 22
// 428.695 us; speedup vs baseline: 1.0497x; 1.0497x over previous
//
#include <hip/hip_runtime.h>
#include <stdint.h>

// FINAL (R22 = R20 = R15, verified best 424us; reproduced twice).
// Pipeline: prep_all (merged conv+weights+bias, 1 dispatch) ->
// gemm1 (128x128 tile, 8 waves, counted-vmcnt double-buffer + T2 XOR swizzle,
// coalesced per-head qkv epilogue: Q[64][32] K[64][32] Vt[32][64]) ->
// fused attn+gemm2 (one block/window, 12 waves = 1 head/wave, swapped-operand
// softmax fully in-register, O via 4-lane transpose to LDS, one barrier,
// then GEMM2 from LDS with L2-resident WmT).
// Session: 654 -> 424us. Fusion-deeper (R17-19: reg spill), occupancy reshape
// (R21), micro-opts (R11/R16) all counter-verified negative and reverted.

typedef __attribute__((ext_vector_type(4))) float f32x4;
typedef __attribute__((ext_vector_type(4))) short s16x4;
typedef __attribute__((ext_vector_type(8))) short s16x8;

#define DEVI static __device__ __forceinline__

DEVI unsigned short f2bf(float f) {
  union { float f; uint32_t u; } v; v.f = f;
  return (unsigned short)((v.u + 0x7FFFu + ((v.u >> 16) & 1u)) >> 16);
}

DEVI uint32_t pk2(float lo, float hi) {
  return (uint32_t)f2bf(lo) | ((uint32_t)f2bf(hi) << 16);
}

DEVI f32x4 zero4() { f32x4 z; z[0] = 0.f; z[1] = 0.f; z[2] = 0.f; z[3] = 0.f; return z; }

#if defined(__has_builtin)
#if __has_builtin(__builtin_amdgcn_mfma_f32_16x16x16bf16_1k)
#define MFMA16_BUILTIN 1
#endif
#if __has_builtin(__builtin_amdgcn_global_load_lds)
#define HAS_GLLDS 1
#endif
#endif

DEVI f32x4 mfma16(s16x4 a, s16x4 b, f32x4 c) {
#ifdef MFMA16_BUILTIN
  return __builtin_amdgcn_mfma_f32_16x16x16bf16_1k(a, b, c, 0, 0, 0);
#else
  asm volatile("v_mfma_f32_16x16x16_bf16 %0, %1, %2, %0" : "+v"(c) : "v"(a), "v"(b));
  return c;
#endif
}

DEVI f32x4 mfma32(s16x8 a, s16x8 b, f32x4 c) {
  return __builtin_amdgcn_mfma_f32_16x16x32_bf16(a, b, c, 0, 0, 0);
}

DEVI void stage1k(const unsigned short* g_lane, unsigned short* lds_base) {
#ifdef HAS_GLLDS
  __builtin_amdgcn_global_load_lds(
      (const __attribute__((address_space(1))) unsigned int*)g_lane,
      (__attribute__((address_space(3))) unsigned int*)lds_base, 16, 0, 0);
#else
  *(s16x8*)(lds_base + (threadIdx.x & 63) * 8) = *(const s16x8*)g_lane;
#endif
}

__global__ void fill_val(float* o, int n, float v) {
  int t = blockIdx.x * 256 + threadIdx.x;
  if (t < n) o[t] = v;
}

// ---------------- merged prep: conv + wqkvT + wmT + bqkv + biasF ----------------
__global__ __launch_bounds__(256) void prep_all(
    const float* __restrict__ x, unsigned short* __restrict__ xb,
    const float* __restrict__ Wqkv, unsigned short* __restrict__ WqkvT,
    const float* __restrict__ Wm, unsigned short* __restrict__ WmT,
    const float* __restrict__ bqkv, float* __restrict__ bqkvs,
    const float* __restrict__ rel, float* __restrict__ biasF) {
  const int b = blockIdx.x;
  if (b < 2048) {
    const size_t nchunk = 131072UL * 384 / 8;
    for (size_t i = (size_t)b * 256 + threadIdx.x; i < nchunk; i += 2048UL * 256) {
      f32x4 a = *(const f32x4*)(x + i * 8);
      f32x4 c = *(const f32x4*)(x + i * 8 + 4);
      s16x8 p;
      p[0] = (short)f2bf(a[0]); p[1] = (short)f2bf(a[1]);
      p[2] = (short)f2bf(a[2]); p[3] = (short)f2bf(a[3]);
      p[4] = (short)f2bf(c[0]); p[5] = (short)f2bf(c[1]);
      p[6] = (short)f2bf(c[2]); p[7] = (short)f2bf(c[3]);
      *(s16x8*)(xb + i * 8) = p;
    }
  } else if (b == 2048) {
    for (int t = threadIdx.x; t < 1152; t += 256)
      bqkvs[t] = bqkv[t] * ((t < 384) ? 0.17677669529663687f : 1.0f);
  } else if (b < 2097) {
    int t = (b - 2049) * 256 + threadIdx.x;  // 12288
    if (t < 12288) {
      int h = t >> 10;
      int r = (t >> 6) & 15;
      int lane = t & 63;
      int jt = r >> 2, it = r & 3;
      int lg = lane >> 4, lr = lane & 15;
      int i = it * 16 + lr;
#pragma unroll
      for (int e = 0; e < 4; ++e) {
        int j = jt * 16 + lg * 4 + e;
        int idx = ((i >> 3) - (j >> 3) + 7) * 15 + ((i & 7) - (j & 7) + 7);
        biasF[t * 4 + e] = rel[idx * 12 + h];
      }
    }
  } else if (b < 2673) {
    int t = (b - 2097) * 256 + threadIdx.x;  // 147456
    int n = t / 384, k = t - n * 384;
    WmT[t] = f2bf(Wm[(size_t)k * 384 + n]);
  } else {
    int t = (b - 2673) * 256 + threadIdx.x;  // 442368
    int n = t / 384, k = t - n * 384;
    float s = (n < 384) ? 0.17677669529663687f : 1.0f;  // SCALE folded into Wq
    WqkvT[t] = f2bf(Wqkv[(size_t)k * 1152 + n] * s);
  }
}

// ---------------- GEMM1 (counted-vmcnt dbuf + T2 swizzle) ----------
template <bool QKV_EPI>
__global__ __launch_bounds__(512, 4) void gemm_k(const unsigned short* __restrict__ A,
                                                 const unsigned short* __restrict__ BT,
                                                 const float* __restrict__ bias,
                                                 void* __restrict__ Cv) {
  constexpr int K = 384;
  constexpr int NT = QKV_EPI ? 9 : 3;
  constexpr int N = NT * 128;
  __shared__ unsigned short sm[2][16384];
  const int bid = blockIdx.x;
  const int swz = (bid & 7) * (NT * 128) + (bid >> 3);  // XCD-aware, bijective
  const int n0 = (swz % NT) * 128;
  const int m0 = (swz / NT) * 128;
  const int tid = threadIdx.x;
  const int lane = tid & 63, wv = tid >> 6;
  const int wr = wv >> 2, wc = wv & 3;
  const int lg = lane >> 4, lr = lane & 15;

  const int scol = ((lane & 7) ^ (lane >> 3)) * 8;
  const unsigned short* Ag = A + (size_t)(m0 + wv * 16 + (lane >> 3)) * K + scol;
  const unsigned short* Bg = BT + (size_t)(n0 + wv * 16 + (lane >> 3)) * K + scol;

  f32x4 acc[4][2];
#pragma unroll
  for (int i = 0; i < 4; ++i)
#pragma unroll
    for (int j = 0; j < 2; ++j) acc[i][j] = zero4();

  auto STAGE = [&](int buf, int k0) {
#pragma unroll
    for (int c2 = 0; c2 < 2; ++c2)
      stage1k(Ag + (size_t)(c2 * 8) * K + k0, &sm[buf][(wv * 16 + c2 * 8) * 64]);
#pragma unroll
    for (int c2 = 0; c2 < 2; ++c2)
      stage1k(Bg + (size_t)(c2 * 8) * K + k0, &sm[buf][8192 + (wv * 16 + c2 * 8) * 64]);
  };
  const int sa = (lr & 7) << 3;
  auto COMPUTE = [&](int buf) {
#pragma unroll
    for (int kk = 0; kk < 64; kk += 32) {
      s16x8 af[4], bf[2];
#pragma unroll
      for (int mt = 0; mt < 4; ++mt)
        af[mt] = *(const s16x8*)&sm[buf][(wr * 64 + 16 * mt + lr) * 64 + ((kk + 8 * lg) ^ sa)];
#pragma unroll
      for (int nt = 0; nt < 2; ++nt)
        bf[nt] = *(const s16x8*)&sm[buf][8192 + (wc * 32 + 16 * nt + lr) * 64 + ((kk + 8 * lg) ^ sa)];
#pragma unroll
      for (int mt = 0; mt < 4; ++mt)
#pragma unroll
        for (int nt = 0; nt < 2; ++nt)
          acc[mt][nt] = mfma32(af[mt], bf[nt], acc[mt][nt]);
    }
  };

  STAGE(0, 0);
  int cur = 0;
#pragma unroll 1
  for (int t = 0; t < 5; ++t) {
    STAGE(cur ^ 1, (t + 1) * 64);
    asm volatile("s_waitcnt vmcnt(4)" ::: "memory");
    __builtin_amdgcn_sched_barrier(0);
    __builtin_amdgcn_s_barrier();
    __builtin_amdgcn_sched_barrier(0);
    COMPUTE(cur);
    __builtin_amdgcn_sched_barrier(0);
    __builtin_amdgcn_s_barrier();
    cur ^= 1;
  }
  asm volatile("s_waitcnt vmcnt(0)" ::: "memory");
  __builtin_amdgcn_sched_barrier(0);
  __builtin_amdgcn_s_barrier();
  __builtin_amdgcn_sched_barrier(0);
  COMPUTE(cur);

  const int crow = m0 + wr * 64 + 4 * lg;
  const int ccol = n0 + wc * 32 + lr;
  if constexpr (QKV_EPI) {
    const int sel = n0 / 384;
    unsigned short* qkv = (unsigned short*)Cv;
    if (sel < 2) {
      unsigned short* tile = &sm[0][0];
#pragma unroll
      for (int nt = 0; nt < 2; ++nt) {
        const int cc = wc * 32 + 16 * nt + lr;
        const float bv = bias[n0 + cc];
#pragma unroll
        for (int mt = 0; mt < 4; ++mt) {
#pragma unroll
          for (int e = 0; e < 4; ++e) {
            const int r = wr * 64 + 16 * mt + 4 * lg + e;
            tile[r * 128 + (cc ^ ((r & 7) << 3))] = f2bf(acc[mt][nt][e] + bv);
          }
        }
      }
      __syncthreads();
      const int hbase = (n0 - sel * 384) >> 5;
      const int tr = wv * 16 + (lane >> 2);
      const int gtok = m0 + tr;
      const int w2 = gtok >> 6, t0r = gtok & 63;
#pragma unroll
      for (int hh = 0; hh < 4; ++hh) {
        const int chunk = hh * 4 + (lane & 3);
        s16x8 v = *(const s16x8*)&tile[tr * 128 + ((chunk * 8) ^ ((tr & 7) << 3))];
        unsigned short* dst = qkv + (((size_t)w2 * 12 + hbase + hh) * 3 + sel) * 2048 +
                              t0r * 32 + (lane & 3) * 8;
        *(s16x8*)dst = v;
      }
    } else {
      const int window = crow >> 6;
      const int t0 = crow & 63;
#pragma unroll
      for (int nt = 0; nt < 2; ++nt) {
        const int col = ccol + 16 * nt;
        const int hcol = col - 768;
        const int h = hcol >> 5, d = hcol & 31;
        const float bv = bias[col];
        unsigned short* base = qkv + (((size_t)window * 12 + h) * 3 + 2) * 2048;
#pragma unroll
        for (int mt = 0; mt < 4; ++mt) {
          s16x4 pk;
#pragma unroll
          for (int e = 0; e < 4; ++e) pk[e] = (short)f2bf(acc[mt][nt][e] + bv);
          *(s16x4*)&base[d * 64 + t0 + 16 * mt] = pk;
        }
      }
    }
  } else {
    float* C = (float*)Cv;
#pragma unroll
    for (int mt = 0; mt < 4; ++mt)
#pragma unroll
      for (int nt = 0; nt < 2; ++nt) {
        const int col = ccol + 16 * nt;
        const float bv = bias[col];
#pragma unroll
        for (int e = 0; e < 4; ++e)
          C[(size_t)(crow + 16 * mt + e) * N + col] = acc[mt][nt][e] + bv;
      }
  }
}

// ---------------- fused attention + GEMM2: one block per window, 12 waves ----------
__global__ __launch_bounds__(768) void attn_gemm2_k(const unsigned short* __restrict__ qkv,
                                                    const float* __restrict__ biasF,
                                                    const unsigned short* __restrict__ WmT,
                                                    const float* __restrict__ bm,
                                                    float* __restrict__ out) {
  __shared__ unsigned short att_s[64 * 392];  // 50176 B
  const int lane = threadIdx.x & 63;
  const int wv = threadIdx.x >> 6;  // 0..11 = head
  const int window = blockIdx.x;    // [0, 2048)
  const int h = wv;
  const int lg = lane >> 4, lr = lane & 15;

  const unsigned short* hb = qkv + ((size_t)window * 12 + h) * 6144;
  const unsigned short* Qh = hb;
  const unsigned short* Kh = hb + 2048;
  const unsigned short* Vth = hb + 4096;

  s16x8 ka[4], qb[4];
#pragma unroll
  for (int jt = 0; jt < 4; ++jt)
    ka[jt] = *(const s16x8*)&Kh[(jt * 16 + lr) * 32 + 8 * lg];
#pragma unroll
  for (int it = 0; it < 4; ++it)
    qb[it] = *(const s16x8*)&Qh[(it * 16 + lr) * 32 + 8 * lg];

  f32x4 c[4][4];
#pragma unroll
  for (int a = 0; a < 4; ++a)
#pragma unroll
    for (int b2 = 0; b2 < 4; ++b2) c[a][b2] = zero4();

#pragma unroll
  for (int jt = 0; jt < 4; ++jt)
#pragma unroll
    for (int it = 0; it < 4; ++it)
      c[jt][it] = mfma32(ka[jt], qb[it], c[jt][it]);

  const f32x4* bF = (const f32x4*)biasF + ((size_t)h * 16) * 64 + lane;
#pragma unroll
  for (int jt = 0; jt < 4; ++jt)
#pragma unroll
    for (int it = 0; it < 4; ++it)
      c[jt][it] += bF[(jt * 4 + it) * 64];

  s16x4 pb[4][4];
#pragma unroll
  for (int it = 0; it < 4; ++it) {
    float m = -3.0e38f;
#pragma unroll
    for (int jt = 0; jt < 4; ++jt)
#pragma unroll
      for (int e = 0; e < 4; ++e) m = fmaxf(m, c[jt][it][e]);
    m = fmaxf(m, __shfl_xor(m, 16));
    m = fmaxf(m, __shfl_xor(m, 32));
    float s = 0.f;
#pragma unroll
    for (int jt = 0; jt < 4; ++jt)
#pragma unroll
      for (int e = 0; e < 4; ++e) {
        float p = __expf(c[jt][it][e] - m);
        c[jt][it][e] = p;
        s += p;
      }
    s += __shfl_xor(s, 16);
    s += __shfl_xor(s, 32);
    const float inv = 1.f / s;
#pragma unroll
    for (int jt = 0; jt < 4; ++jt) {
      s16x4 pk;
#pragma unroll
      for (int e = 0; e < 4; ++e) pk[e] = (short)f2bf(c[jt][it][e] * inv);
      pb[jt][it] = pk;
    }
  }

  f32x4 o[2][4];
#pragma unroll
  for (int a = 0; a < 2; ++a)
#pragma unroll
    for (int b2 = 0; b2 < 4; ++b2) o[a][b2] = zero4();

#pragma unroll
  for (int jt = 0; jt < 4; ++jt) {
    s16x4 va[2];
#pragma unroll
    for (int dt = 0; dt < 2; ++dt)
      va[dt] = *(const s16x4*)&Vth[(dt * 16 + lr) * 64 + jt * 16 + 4 * lg];
#pragma unroll
    for (int dt = 0; dt < 2; ++dt)
#pragma unroll
      for (int it = 0; it < 4; ++it)
        o[dt][it] = mfma16(va[dt], pb[jt][it], o[dt][it]);
  }

  // 4-lane transpose -> LDS: lane lg holds d[8lg,8lg+8) of token it*16+lr.
#pragma unroll
  for (int it = 0; it < 4; ++it) {
    const uint32_t p0 = pk2(o[0][it][0], o[0][it][1]);
    const uint32_t p1 = pk2(o[0][it][2], o[0][it][3]);
    const uint32_t q0 = pk2(o[1][it][0], o[1][it][1]);
    const uint32_t q1 = pk2(o[1][it][2], o[1][it][3]);

    const uint32_t x16_0 = __shfl_xor((int)(lg == 2 ? q0 : p0), 16);
    const uint32_t x16_1 = __shfl_xor((int)(lg == 2 ? q1 : p1), 16);
    const uint32_t x32_0 = __shfl_xor((int)(lg == 0 ? q0 : p0), 32);
    const uint32_t x32_1 = __shfl_xor((int)(lg == 0 ? q1 : p1), 32);
    const uint32_t x48_0 = __shfl_xor((int)(lg == 1 ? q0 : p0), 48);
    const uint32_t x48_1 = __shfl_xor((int)(lg == 1 ? q1 : p1), 48);

    uint32_t w[4];
    w[0] = lg == 0 ? p0 : lg == 1 ? x48_0 : lg == 2 ? x32_0 : x16_0;
    w[1] = lg == 0 ? p1 : lg == 1 ? x48_1 : lg == 2 ? x32_1 : x16_1;
    w[2] = lg == 0 ? x16_0 : lg == 1 ? x32_0 : lg == 2 ? x48_0 : q0;
    w[3] = lg == 0 ? x16_1 : lg == 1 ? x32_1 : lg == 2 ? x48_1 : q1;

    *(uint4*)&att_s[(size_t)(it * 16 + lr) * 392 + h * 32 + 8 * lg] =
        make_uint4(w[0], w[1], w[2], w[3]);
  }

  __syncthreads();

  // ---- phase 2: GEMM2. wave wv -> output cols [wv*32, wv*32+32)
  f32x4 acc[4][2];
#pragma unroll
  for (int mt = 0; mt < 4; ++mt)
#pragma unroll
    for (int nt = 0; nt < 2; ++nt) acc[mt][nt] = zero4();

  const int n0w = wv * 32;
#pragma unroll 2
  for (int ks = 0; ks < 12; ++ks) {
    s16x8 af[4], bf[2];
#pragma unroll
    for (int mt = 0; mt < 4; ++mt)
      af[mt] = *(const s16x8*)&att_s[(16 * mt + lr) * 392 + ks * 32 + 8 * lg];
#pragma unroll
    for (int nt = 0; nt < 2; ++nt)
      bf[nt] = *(const s16x8*)&WmT[(size_t)(n0w + 16 * nt + lr) * 384 + ks * 32 + 8 * lg];
#pragma unroll
    for (int mt = 0; mt < 4; ++mt)
#pragma unroll
      for (int nt = 0; nt < 2; ++nt)
        acc[mt][nt] = mfma32(af[mt], bf[nt], acc[mt][nt]);
  }

  float* ob = out + (size_t)window * 64 * 384;
#pragma unroll
  for (int mt = 0; mt < 4; ++mt)
#pragma unroll
    for (int nt = 0; nt < 2; ++nt) {
      const int col = n0w + 16 * nt + lr;
      const float bv = bm[col];
#pragma unroll
      for (int e = 0; e < 4; ++e)
        ob[(size_t)(16 * mt + 4 * lg + e) * 384 + col] = acc[mt][nt][e] + bv;
    }
}

extern "C" void kernel_launch(void* const* d_in, const int* in_sizes, int n_in,
                              void* d_out, int out_size, void* d_ws, size_t ws_size,
                              hipStream_t stream) {
  const float* x = (const float*)d_in[0];
  const float* Wqkv = (const float*)d_in[1];
  const float* bqkv = (const float*)d_in[2];
  const float* Wm = (const float*)d_in[3];
  const float* bm = (const float*)d_in[4];
  const float* rel = (const float*)d_in[5];

  const size_t M = 131072;  // B*G*P
  char* ws = (char*)d_ws;
  size_t off = 0;
  unsigned short* qkv = (unsigned short*)(ws + off);   off += M * 1152 * 2;  // 302 MB
  unsigned short* xb = (unsigned short*)(ws + off);    off += M * 384 * 2;   // 100 MB
  unsigned short* WqkvT = (unsigned short*)(ws + off); off += 1152 * 384 * 2;
  unsigned short* WmT = (unsigned short*)(ws + off);   off += 384 * 384 * 2;
  float* biasF = (float*)(ws + off);                   off += 12 * 16 * 64 * 4 * 4;
  float* bqkvs = (float*)(ws + off);                   off += 1152 * 4;

  if (ws_size < off) {
    fill_val<<<(out_size + 255) / 256, 256, 0, stream>>>((float*)d_out, out_size, 12345.0f);
    return;
  }

  prep_all<<<4401, 256, 0, stream>>>(x, xb, Wqkv, WqkvT, Wm, WmT, bqkv, bqkvs, rel, biasF);
  gemm_k<true><<<9216, 512, 0, stream>>>(xb, WqkvT, bqkvs, qkv);
  attn_gemm2_k<<<2048, 768, 0, stream>>>(qkv, biasF, WmT, bm, (float*)d_out);
}